// Round 20
// baseline (490.940 us; speedup 1.0000x reference)
//
#include <hip/hip_runtime.h>
#include <hip/hip_bf16.h>

#define B_   4096
#define T_   200
#define KA   16

// ---- workspace layout (float offsets) ----
#define OFF_BG  0
#define OFF_WQ  4096
#define OFF_QP  (OFF_BG  + B_*T_)
#define OFF_UI1 (OFF_QP  + B_*64)
#define OFF_UI2 (OFF_UI1 + B_*64)
#define OFF_HF  (OFF_UI2 + B_*64)
#define OFF_CL  (OFF_HF  + B_*64)

typedef __attribute__((ext_vector_type(8))) short bf16x8;
typedef __attribute__((ext_vector_type(4))) float f32x4;

__device__ __forceinline__ float sigmoidf_(float x) {
  return 1.f / (1.f + __expf(-x));
}
__device__ __forceinline__ float sigf(float x) {
  return __builtin_amdgcn_rcpf(1.f + __builtin_amdgcn_exp2f(-1.44269504f * x));
}
__device__ __forceinline__ float tanhfast(float y) {
  return 1.f - 2.f * __builtin_amdgcn_rcpf(1.f + __builtin_amdgcn_exp2f(2.88539008f * y));
}
__device__ __forceinline__ short f2bf(float x) {
  unsigned u = __float_as_uint(x);
  unsigned r = (u + 0x7fffu + ((u >> 16) & 1u)) >> 16;
  return (short)r;
}
__device__ __forceinline__ unsigned cvtpk(float lo, float hi) {
  unsigned r;
  asm("v_cvt_pk_bf16_f32 %0, %1, %2" : "=v"(r) : "v"(lo), "v"(hi));
  return r;
}
union BF8 { bf16x8 v; unsigned u[4]; };

__device__ __forceinline__ bf16x8 pack8(float4 f0, float4 f1) {
  BF8 a;
  a.u[0] = cvtpk(f0.x, f0.y);
  a.u[1] = cvtpk(f0.z, f0.w);
  a.u[2] = cvtpk(f1.x, f1.y);
  a.u[3] = cvtpk(f1.z, f1.w);
  return a.v;
}
__device__ __forceinline__ bf16x8 pack8m(float4 f0, float4 f1,
                                         float4 q0, float4 q1) {
  BF8 a;
  a.u[0] = cvtpk(f0.x*q0.x, f0.y*q0.y);
  a.u[1] = cvtpk(f0.z*q0.z, f0.w*q0.w);
  a.u[2] = cvtpk(f1.x*q1.x, f1.y*q1.y);
  a.u[3] = cvtpk(f1.z*q1.z, f1.w*q1.w);
  return a.v;
}

// bg layout: fragment-contiguous bf16. For k=0..127, col=0..63:
//   dst = ((k>>5)*4 + ((k>>3)&3))*512 + col*8 + (k&7)

// ============================================================
// K0: one-shot weight prep
// ============================================================
__global__ __launch_bounds__(256) void k_prep(
    const float* __restrict__ auW1, short* __restrict__ bg,
    float* __restrict__ wq)
{
  const int i = blockIdx.x*256 + threadIdx.x;
  if (i < 8192) {
    const int k = i >> 6, col = i & 63;
    float v;
    if (k < 64) v = auW1[k*64 + col] + auW1[2*4096 + k*64 + col];
    else        v = auW1[3*4096 + (k-64)*64 + col];
    bg[((k >> 5)*4 + ((k >> 3) & 3))*512 + col*8 + (k & 7)] = f2bf(v);
  } else if (i < 12288) {
    const int j = i - 8192;
    wq[j] = auW1[(64 + (j >> 6))*64 + (j & 63)]
          - auW1[(128 + (j >> 6))*64 + (j & 63)];
  }
}

// ============================================================
// K1 (MFMA, fused): act-unit + softmax/cluster + ui1.
//   R10 structure.  __launch_bounds__(256,6) pins VGPR<=80 (the
//   allocation that measured 174us / 6 blocks/CU on the old toolchain).
// ============================================================
__global__ __launch_bounds__(256, 6) void k_act1(
    const int* __restrict__ item_id, const int* __restrict__ hist_ids,
    const int* __restrict__ attrs,
    const float* __restrict__ emb, const float* __restrict__ aub1,
    const float* __restrict__ auW2, const float* __restrict__ aub2,
    const short* __restrict__ bg_in, const float* __restrict__ wq_in,
    float* __restrict__ qp_out, float* __restrict__ ui1_out,
    float* __restrict__ cluster_out)
{
  __shared__ __align__(16) char sPool[16384];   // sB2 (16KB) then sAcc (16KB)
  __shared__ float sW1[208];
  __shared__ float sP[200];
  __shared__ float sM[KA], sE[KA];
  __shared__ float sItem[64], sQp[64];
  __shared__ float sQpP[4][64];
  __shared__ float sUi[4][64];
  __shared__ int   sIds[200], sAttr[200];

  short* sB2 = (short*)sPool;
  float (*sAcc)[KA][64] = (float (*)[KA][64])sPool;

  const int b = blockIdx.x;
  const int tid = threadIdx.x;
  const int wave = tid >> 6, lane = tid & 63;
  const int g = lane >> 4;
  const int c15 = lane & 15;
  const int itrow = item_id[b];

  for (int i = tid; i < 4096; i += 256)
    ((unsigned*)sB2)[i] = ((const unsigned*)bg_in)[i];
  if (tid < 64) sItem[tid] = emb[(size_t)itrow*64 + tid];
  if (tid < T_) {
    sIds[tid]  = hist_ids[(size_t)b*T_ + tid];
    sAttr[tid] = attrs[(size_t)b*T_ + tid];
  }
  __syncthreads();

  {
    const int j = tid & 63, iq = tid >> 6;
    float acc = 0.f;
    #pragma unroll
    for (int ii = 0; ii < 16; ++ii) {
      const int i = iq*16 + ii;
      acc += sItem[i] * wq_in[i*64 + j];
    }
    sQpP[iq][j] = acc;
  }
  __syncthreads();
  if (tid < 64) {
    float q = aub1[tid] + sQpP[0][tid] + sQpP[1][tid] + sQpP[2][tid] + sQpP[3][tid];
    sQp[tid] = q;
    qp_out[(size_t)b*64 + tid] = q;
  }
  __syncthreads();

  const float4* itemp = (const float4*)(emb + (size_t)itrow*64);
  float4 q0 = itemp[g*2],     q1 = itemp[g*2 + 1];
  float4 q2 = itemp[8 + g*2], q3 = itemp[8 + g*2 + 1];

  bf16x8 bfr[4][4];
  #pragma unroll
  for (int kk = 0; kk < 4; ++kk) {
    #pragma unroll
    for (int n = 0; n < 4; ++n)
      bfr[kk][n] = *(const bf16x8*)&sB2[(kk*4 + g)*512 + (n*16 + c15)*8];
  }
  float w2v[4], qpv[4];
  #pragma unroll
  for (int n = 0; n < 4; ++n) {
    w2v[n] = auW2[n*16 + c15];
    qpv[n] = sQp[n*16 + c15];
  }
  const float b2v = aub2[0];
  __syncthreads();                 // all waves done reading sB2

  for (int i = tid; i < 4*KA*64; i += 256) ((float*)sAcc)[i] = 0.f;

  {
    float4 c0, c1, c2, c3;
    {
      const int t = wave*16 + c15;
      const int tc = (t < T_) ? t : (T_ - 1);
      const float4* kp = (const float4*)(emb + (size_t)sIds[tc]*64);
      c0 = kp[g*2];     c1 = kp[g*2 + 1];
      c2 = kp[8 + g*2]; c3 = kp[8 + g*2 + 1];
    }
    for (int tt = wave; tt < 13; tt += 4) {
      float4 n0{0,0,0,0}, n1{0,0,0,0}, n2{0,0,0,0}, n3{0,0,0,0};
      const int ttn = tt + 4;
      if (ttn < 13) {
        const int t = ttn*16 + c15;
        const int tc = (t < T_) ? t : (T_ - 1);
        const float4* kp = (const float4*)(emb + (size_t)sIds[tc]*64);
        n0 = kp[g*2];     n1 = kp[g*2 + 1];
        n2 = kp[8 + g*2]; n3 = kp[8 + g*2 + 1];
      }

      bf16x8 a0 = pack8(c0, c1);
      bf16x8 a1 = pack8(c2, c3);
      bf16x8 a2 = pack8m(c0, c1, q0, q1);
      bf16x8 a3 = pack8m(c2, c3, q2, q3);

      f32x4 acc[4];
      #pragma unroll
      for (int n = 0; n < 4; ++n) acc[n] = f32x4{qpv[n], qpv[n], qpv[n], qpv[n]};
      #pragma unroll
      for (int n = 0; n < 4; ++n) {
        acc[n] = __builtin_amdgcn_mfma_f32_16x16x32_bf16(a0, bfr[0][n], acc[n], 0, 0, 0);
        acc[n] = __builtin_amdgcn_mfma_f32_16x16x32_bf16(a1, bfr[1][n], acc[n], 0, 0, 0);
        acc[n] = __builtin_amdgcn_mfma_f32_16x16x32_bf16(a2, bfr[2][n], acc[n], 0, 0, 0);
        acc[n] = __builtin_amdgcn_mfma_f32_16x16x32_bf16(a3, bfr[3][n], acc[n], 0, 0, 0);
      }
      float ws[4] = {0.f, 0.f, 0.f, 0.f};
      #pragma unroll
      for (int n = 0; n < 4; ++n) {
        #pragma unroll
        for (int r = 0; r < 4; ++r)
          ws[r] += fmaxf(acc[n][r], 0.f) * w2v[n];
      }
      #pragma unroll
      for (int r = 0; r < 4; ++r) {
        ws[r] += __shfl_xor(ws[r], 1);
        ws[r] += __shfl_xor(ws[r], 2);
        ws[r] += __shfl_xor(ws[r], 4);
        ws[r] += __shfl_xor(ws[r], 8);
        ws[r] += b2v;
      }
      if (c15 == 0) {
        #pragma unroll
        for (int r = 0; r < 4; ++r) {
          const int trow = tt*16 + g*4 + r;
          if (trow < T_) sW1[trow] = ws[r];
        }
      }
      c0 = n0; c1 = n1; c2 = n2; c3 = n3;
    }
  }
  __syncthreads();

  for (int k = wave; k < KA; k += 4) {
    float m = -1e9f;
    for (int tt4 = 0; tt4 < 4; ++tt4) {
      int t = tt4*64 + lane;
      if (t < T_ && sAttr[t] == k) m = fmaxf(m, sW1[t]);
    }
    #pragma unroll
    for (int off = 32; off > 0; off >>= 1) m = fmaxf(m, __shfl_xor(m, off));
    float e = 0.f;
    for (int tt4 = 0; tt4 < 4; ++tt4) {
      int t = tt4*64 + lane;
      if (t < T_ && sAttr[t] == k) e += __expf(sW1[t] - m);
    }
    #pragma unroll
    for (int off = 32; off > 0; off >>= 1) e += __shfl_xor(e, off);
    if (lane == 0) { sM[k] = m; sE[k] = e; }
  }
  __syncthreads();
  if (tid < T_) {
    int k = sAttr[tid];
    float e = sE[k];
    sP[tid] = (e > 0.f) ? __expf(sW1[tid] - sM[k]) * __builtin_amdgcn_rcpf(e) : 0.f;
  }
  __syncthreads();

  {
    float uiacc = 0.f;
    float vcur = emb[(size_t)sIds[wave]*64 + lane];
    for (int t = wave; t < T_; t += 4) {
      const int tn = t + 4;
      float vnext = 0.f;
      if (tn < T_) vnext = emb[(size_t)sIds[tn]*64 + lane];
      const int k = sAttr[t];
      sAcc[wave][k][lane] += sP[t] * vcur;
      uiacc += sW1[t] * vcur;
      vcur = vnext;
    }
    sUi[wave][lane] = uiacc;
  }
  __syncthreads();

  for (int i = tid; i < KA*64; i += 256) {
    cluster_out[(size_t)b*(KA*64) + i] =
        sAcc[0][0][i] + sAcc[1][0][i] + sAcc[2][0][i] + sAcc[3][0][i];
  }
  if (tid < 64) {
    ui1_out[(size_t)b*64 + tid] =
        sUi[0][tid] + sUi[1][tid] + sUi[2][tid] + sUi[3][tid];
  }
}

// ============================================================
// K3 (MFMA): GRU, 16 rows/block, producer-consumer.
// ============================================================
#define GRU_ROWS 16
__global__ __launch_bounds__(512) void k_gru(
    const int* __restrict__ hist_ids, const float* __restrict__ emb,
    const float* __restrict__ Wx, const float* __restrict__ Wh,
    const float* __restrict__ gb, float* __restrict__ hfin_out)
{
  __shared__ short sH[2][16*64];
  __shared__ short sX[4][16*64];
  __shared__ int   sIds[16*200];

  const int tid  = threadIdx.x;
  const int w    = tid >> 6;
  const int lane = tid & 63;
  const int g    = lane >> 4;
  const int c15  = lane & 15;
  const int b0   = blockIdx.x * GRU_ROWS;

  for (int i = tid; i < 16*200; i += 512) {
    const int r = i / 200, t = i - r*200;
    sIds[i] = hist_ids[(size_t)(b0 + r)*T_ + t];
  }
  for (int i = tid; i < 16*64; i += 512) sH[0][i] = 0;
  __syncthreads();

  if (w >= 4) {
    const int stane = (w - 4)*64 + lane;
    const int srow  = stane >> 4;
    const int scol  = (stane & 15) * 4;
    const int sidx  = srow*64 + (((scol >> 3) ^ (srow & 7))*8) + (scol & 7);
    const int* idrow = &sIds[srow*200];
    #pragma unroll
    for (int p = 0; p < 2; ++p) {
      const float4 f = *(const float4*)(emb + (size_t)idrow[p]*64 + scol);
      uint2 u; u.x = cvtpk(f.x, f.y); u.y = cvtpk(f.z, f.w);
      *(uint2*)&sX[p][sidx] = u;
    }
    __syncthreads();
    for (int t = 0; t < T_; ++t) {
      const int t2 = (t + 2 < T_) ? (t + 2) : (T_ - 1);
      const float4 f = *(const float4*)(emb + (size_t)idrow[t2]*64 + scol);
      uint2 u; u.x = cvtpk(f.x, f.y); u.y = cvtpk(f.z, f.w);
      *(uint2*)&sX[(t + 2) & 3][sidx] = u;
      __syncthreads();
    }
  } else {
    bf16x8 bx[3][2], bh[3][2];
    #pragma unroll
    for (int l = 0; l < 3; ++l) {
      const int jb = (l*4 + w)*16 + c15;
      #pragma unroll
      for (int kk = 0; kk < 2; ++kk) {
        bf16x8 vx, vh;
        #pragma unroll
        for (int e = 0; e < 8; ++e) {
          const int krow = kk*32 + g*8 + e;
          vx[e] = f2bf(Wx[(size_t)krow*192 + jb]);
          vh[e] = f2bf(Wh[(size_t)krow*192 + jb]);
        }
        bx[l][kk] = vx; bh[l][kk] = vh;
      }
    }
    float bias[3];
    #pragma unroll
    for (int l = 0; l < 3; ++l) bias[l] = gb[l*64 + w*16 + c15];

    const int rs = c15 & 7;
    const int ridx0 = c15*64 + ((g    ) ^ rs)*8;
    const int ridx1 = c15*64 + ((g + 4) ^ rs)*8;
    int widx[4];
    {
      const int unit = w*2 + (c15 >> 3);
      #pragma unroll
      for (int r = 0; r < 4; ++r) {
        const int row = g*4 + r;
        widx[r] = row*64 + ((unit ^ (row & 7))*8) + (c15 & 7);
      }
    }
    float hold[4] = {0.f, 0.f, 0.f, 0.f};
    __syncthreads();

    #pragma unroll 2
    for (int t = 0; t < T_; ++t) {
      const short* hbuf = sH[t & 1];
      short*       hnxt = sH[(t & 1) ^ 1];
      const short* xbuf = sX[t & 3];

      bf16x8 ax0 = *(const bf16x8*)&xbuf[ridx0];
      bf16x8 ax1 = *(const bf16x8*)&xbuf[ridx1];
      bf16x8 ah0 = *(const bf16x8*)&hbuf[ridx0];
      bf16x8 ah1 = *(const bf16x8*)&hbuf[ridx1];

      f32x4 aX[3], aH[3];
      #pragma unroll
      for (int l = 0; l < 3; ++l) {
        aX[l] = f32x4{bias[l], bias[l], bias[l], bias[l]};
        aH[l] = f32x4{0.f, 0.f, 0.f, 0.f};
      }
      #pragma unroll
      for (int l = 0; l < 3; ++l) {
        aH[l] = __builtin_amdgcn_mfma_f32_16x16x32_bf16(ah0, bh[l][0], aH[l], 0, 0, 0);
        aH[l] = __builtin_amdgcn_mfma_f32_16x16x32_bf16(ah1, bh[l][1], aH[l], 0, 0, 0);
        aX[l] = __builtin_amdgcn_mfma_f32_16x16x32_bf16(ax0, bx[l][0], aX[l], 0, 0, 0);
        aX[l] = __builtin_amdgcn_mfma_f32_16x16x32_bf16(ax1, bx[l][1], aX[l], 0, 0, 0);
      }

      #pragma unroll
      for (int r = 0; r < 4; ++r) {
        float z  = sigf(aX[0][r] + aH[0][r]);
        float rr = sigf(aX[1][r] + aH[1][r]);
        float nn = tanhfast(aX[2][r] + rr * aH[2][r]);
        hold[r] = nn + z * (hold[r] - nn);
        hnxt[widx[r]] = f2bf(hold[r]);
      }
      __syncthreads();
    }

    #pragma unroll
    for (int r = 0; r < 4; ++r)
      hfin_out[(size_t)(b0 + g*4 + r)*64 + w*16 + c15] = hold[r];
  }
}

// ============================================================
// K4 (MFMA): activation unit over 16 clusters -> ui_l2[b,64]
// ============================================================
__global__ __launch_bounds__(256) void k_act2(
    const int* __restrict__ item_id, const float* __restrict__ emb,
    const float* __restrict__ auW2, const float* __restrict__ aub2,
    const float* __restrict__ qp_in, const float* __restrict__ cluster_in,
    const short* __restrict__ bg_in, float* __restrict__ ui2_out)
{
  __shared__ short sB2[8192];
  __shared__ float sWs[4][16];
  __shared__ float sWf[16];
  __shared__ float sUi[4][64];

  const int b = blockIdx.x;
  const int tid = threadIdx.x;
  const int wave = tid >> 6, lane = tid & 63;
  const int g = lane >> 4;
  const int c15 = lane & 15;
  const int itrow = item_id[b];

  for (int i = tid; i < 4096; i += 256)
    ((unsigned*)sB2)[i] = ((const unsigned*)bg_in)[i];
  __syncthreads();

  const float4* itemp = (const float4*)(emb + (size_t)itrow*64);
  float4 q0 = itemp[g*2],     q1 = itemp[g*2 + 1];
  float4 q2 = itemp[8 + g*2], q3 = itemp[8 + g*2 + 1];
  const float4* kp = (const float4*)(cluster_in + (size_t)b*(KA*64) + c15*64);
  float4 k0 = kp[g*2],     k1 = kp[g*2 + 1];
  float4 k2 = kp[8 + g*2], k3 = kp[8 + g*2 + 1];
  bf16x8 a0 = pack8(k0, k1);
  bf16x8 a1 = pack8(k2, k3);
  bf16x8 a2 = pack8m(k0, k1, q0, q1);
  bf16x8 a3 = pack8m(k2, k3, q2, q3);

  const float qpv = qp_in[(size_t)b*64 + wave*16 + c15];
  const float w2v = auW2[wave*16 + c15];
  f32x4 acc = f32x4{qpv, qpv, qpv, qpv};
  acc = __builtin_amdgcn_mfma_f32_16x16x32_bf16(a0, *(const bf16x8*)&sB2[(0*4+g)*512 + (wave*16+c15)*8], acc, 0, 0, 0);
  acc = __builtin_amdgcn_mfma_f32_16x16x32_bf16(a1, *(const bf16x8*)&sB2[(1*4+g)*512 + (wave*16+c15)*8], acc, 0, 0, 0);
  acc = __builtin_amdgcn_mfma_f32_16x16x32_bf16(a2, *(const bf16x8*)&sB2[(2*4+g)*512 + (wave*16+c15)*8], acc, 0, 0, 0);
  acc = __builtin_amdgcn_mfma_f32_16x16x32_bf16(a3, *(const bf16x8*)&sB2[(3*4+g)*512 + (wave*16+c15)*8], acc, 0, 0, 0);

  float ws[4];
  #pragma unroll
  for (int r = 0; r < 4; ++r) {
    float v = fmaxf(acc[r], 0.f) * w2v;
    v += __shfl_xor(v, 1);
    v += __shfl_xor(v, 2);
    v += __shfl_xor(v, 4);
    v += __shfl_xor(v, 8);
    ws[r] = v;
  }
  if (c15 == 0) {
    #pragma unroll
    for (int r = 0; r < 4; ++r) sWs[wave][g*4 + r] = ws[r];
  }
  __syncthreads();
  if (tid < KA)
    sWf[tid] = sWs[0][tid] + sWs[1][tid] + sWs[2][tid] + sWs[3][tid] + aub2[0];
  __syncthreads();

  float uiacc = 0.f;
  #pragma unroll
  for (int kk = 0; kk < 4; ++kk) {
    const int k = wave*4 + kk;
    uiacc += sWf[k] * cluster_in[(size_t)b*(KA*64) + k*64 + lane];
  }
  sUi[wave][lane] = uiacc;
  __syncthreads();
  if (tid < 64) {
    ui2_out[(size_t)b*64 + tid] =
        sUi[0][tid] + sUi[1][tid] + sUi[2][tid] + sUi[3][tid];
  }
}

// ============================================================
// K5: final MLP
// ============================================================
#define MLP_ROWS 16
__global__ __launch_bounds__(256) void k_mlp(
    const int* __restrict__ item_id, const float* __restrict__ emb,
    const float* __restrict__ ui1, const float* __restrict__ ui2,
    const float* __restrict__ hfin,
    const float* __restrict__ W0, const float* __restrict__ b0,
    const float* __restrict__ W1, const float* __restrict__ b1,
    const float* __restrict__ fW, const float* __restrict__ fb,
    float* __restrict__ out)
{
  __shared__ float sC[MLP_ROWS][256];
  __shared__ float sX0[MLP_ROWS][256];
  __shared__ float sX1[MLP_ROWS][128];
  const int tid = threadIdx.x;
  const int rb  = blockIdx.x * MLP_ROWS;

  for (int idx = tid; idx < MLP_ROWS*256; idx += 256) {
    int r = idx >> 8, c = idx & 255;
    size_t row = (size_t)(rb + r);
    float v;
    if (c < 64)       v = ui1[row*64 + c];
    else if (c < 128) v = ui2[row*64 + (c-64)];
    else if (c < 192) v = hfin[row*64 + (c-128)];
    else              v = emb[(size_t)item_id[row]*64 + (c-192)];
    sC[r][c] = v;
  }
  __syncthreads();
  {
    float acc[MLP_ROWS];
    #pragma unroll
    for (int r = 0; r < MLP_ROWS; ++r) acc[r] = b0[tid];
    #pragma unroll 4
    for (int i = 0; i < 256; ++i) {
      float w = W0[(size_t)i*256 + tid];
      #pragma unroll
      for (int r = 0; r < MLP_ROWS; ++r) acc[r] += sC[r][i] * w;
    }
    #pragma unroll
    for (int r = 0; r < MLP_ROWS; ++r) sX0[r][tid] = fmaxf(acc[r], 0.f);
  }
  __syncthreads();
  if (tid < 128) {
    float acc[MLP_ROWS];
    #pragma unroll
    for (int r = 0; r < MLP_ROWS; ++r) acc[r] = b1[tid];
    #pragma unroll 4
    for (int i = 0; i < 256; ++i) {
      float w = W1[(size_t)i*128 + tid];
      #pragma unroll
      for (int r = 0; r < MLP_ROWS; ++r) acc[r] += sX0[r][i] * w;
    }
    #pragma unroll
    for (int r = 0; r < MLP_ROWS; ++r) sX1[r][tid] = fmaxf(acc[r], 0.f);
  }
  __syncthreads();
  {
    int r = tid >> 4, l16 = tid & 15;
    float p = 0.f;
    for (int i = l16; i < 128; i += 16) p += sX1[r][i] * fW[i];
    #pragma unroll
    for (int off = 8; off > 0; off >>= 1) p += __shfl_xor(p, off);
    if (l16 == 0) {
      float logit = p + fb[0];
      out[rb + r] = sigmoidf_(logit);
    }
  }
}

// ============================================================
extern "C" void kernel_launch(void* const* d_in, const int* in_sizes, int n_in,
                              void* d_out, int out_size, void* d_ws, size_t ws_size,
                              hipStream_t stream)
{
  const int*   item_id  = (const int*)d_in[0];
  const int*   hist_ids = (const int*)d_in[1];
  const int*   attrs    = (const int*)d_in[2];
  const float* emb      = (const float*)d_in[3];
  const float* auW1     = (const float*)d_in[4];
  const float* aub1     = (const float*)d_in[5];
  const float* auW2     = (const float*)d_in[6];
  const float* aub2     = (const float*)d_in[7];
  const float* gWx      = (const float*)d_in[8];
  const float* gWh      = (const float*)d_in[9];
  const float* gb       = (const float*)d_in[10];
  const float* W0       = (const float*)d_in[11];
  const float* b0       = (const float*)d_in[12];
  const float* W1       = (const float*)d_in[13];
  const float* b1       = (const float*)d_in[14];
  const float* fW       = (const float*)d_in[15];
  const float* fb       = (const float*)d_in[16];

  float* out = (float*)d_out;
  float* ws  = (float*)d_ws;
  short* bg      = (short*)(ws + OFF_BG);
  float* wq      = ws + OFF_WQ;
  float* qp      = ws + OFF_QP;
  float* ui1     = ws + OFF_UI1;
  float* ui2     = ws + OFF_UI2;
  float* hfin    = ws + OFF_HF;
  float* cluster = ws + OFF_CL;

  k_prep<<<48, 256, 0, stream>>>(auW1, bg, wq);
  k_act1<<<B_, 256, 0, stream>>>(item_id, hist_ids, attrs, emb, aub1,
                                 auW2, aub2, bg, wq, qp, ui1, cluster);
  k_gru<<<B_/GRU_ROWS, 512, 0, stream>>>(hist_ids, emb, gWx, gWh, gb, hfin);
  k_act2<<<B_, 256, 0, stream>>>(item_id, emb, auW2, aub2, qp, cluster, bg,
                                 ui2);
  k_mlp<<<B_/MLP_ROWS, 256, 0, stream>>>(item_id, emb, ui1, ui2, hfin,
                                         W0, b0, W1, b1, fW, fb, out);
}

// Round 21
// 324.991 us; speedup vs baseline: 1.5106x; 1.5106x over previous
//
#include <hip/hip_runtime.h>
#include <hip/hip_bf16.h>

#define B_   4096
#define T_   200
#define KA   16

// ---- workspace layout (float offsets) ----
#define OFF_BG  0
#define OFF_WQ  4096
#define OFF_QP  (OFF_BG  + B_*T_)
#define OFF_UI1 (OFF_QP  + B_*64)
#define OFF_UI2 (OFF_UI1 + B_*64)
#define OFF_HF  (OFF_UI2 + B_*64)
#define OFF_CL  (OFF_HF  + B_*64)

typedef __attribute__((ext_vector_type(8))) short bf16x8;
typedef __attribute__((ext_vector_type(4))) float f32x4;

__device__ __forceinline__ float sigmoidf_(float x) {
  return 1.f / (1.f + __expf(-x));
}
__device__ __forceinline__ float sigf(float x) {
  return __builtin_amdgcn_rcpf(1.f + __builtin_amdgcn_exp2f(-1.44269504f * x));
}
__device__ __forceinline__ float tanhfast(float y) {
  return 1.f - 2.f * __builtin_amdgcn_rcpf(1.f + __builtin_amdgcn_exp2f(2.88539008f * y));
}
__device__ __forceinline__ short f2bf(float x) {
  unsigned u = __float_as_uint(x);
  unsigned r = (u + 0x7fffu + ((u >> 16) & 1u)) >> 16;
  return (short)r;
}
__device__ __forceinline__ unsigned cvtpk(float lo, float hi) {
  unsigned r;
  asm("v_cvt_pk_bf16_f32 %0, %1, %2" : "=v"(r) : "v"(lo), "v"(hi));
  return r;
}
union BF8 { bf16x8 v; unsigned u[4]; };

__device__ __forceinline__ bf16x8 pack8(float4 f0, float4 f1) {
  BF8 a;
  a.u[0] = cvtpk(f0.x, f0.y);
  a.u[1] = cvtpk(f0.z, f0.w);
  a.u[2] = cvtpk(f1.x, f1.y);
  a.u[3] = cvtpk(f1.z, f1.w);
  return a.v;
}
__device__ __forceinline__ bf16x8 pack8m(float4 f0, float4 f1,
                                         float4 q0, float4 q1) {
  BF8 a;
  a.u[0] = cvtpk(f0.x*q0.x, f0.y*q0.y);
  a.u[1] = cvtpk(f0.z*q0.z, f0.w*q0.w);
  a.u[2] = cvtpk(f1.x*q1.x, f1.y*q1.y);
  a.u[3] = cvtpk(f1.z*q1.z, f1.w*q1.w);
  return a.v;
}

// bg layout: fragment-contiguous bf16. For k=0..127, col=0..63:
//   dst = ((k>>5)*4 + ((k>>3)&3))*512 + col*8 + (k&7)

// ============================================================
// K0: one-shot weight prep
// ============================================================
__global__ __launch_bounds__(256) void k_prep(
    const float* __restrict__ auW1, short* __restrict__ bg,
    float* __restrict__ wq)
{
  const int i = blockIdx.x*256 + threadIdx.x;
  if (i < 8192) {
    const int k = i >> 6, col = i & 63;
    float v;
    if (k < 64) v = auW1[k*64 + col] + auW1[2*4096 + k*64 + col];
    else        v = auW1[3*4096 + (k-64)*64 + col];
    bg[((k >> 5)*4 + ((k >> 3) & 3))*512 + col*8 + (k & 7)] = f2bf(v);
  } else if (i < 12288) {
    const int j = i - 8192;
    wq[j] = auW1[(64 + (j >> 6))*64 + (j & 63)]
          - auW1[(128 + (j >> 6))*64 + (j & 63)];
  }
}

// ============================================================
// K1 (MFMA, fused): act-unit + softmax/cluster + ui1.
//   R10 structure minus the MFMA-phase tile prefetch (reduces VGPR
//   pressure ~16 regs so natural allocation lands <=85 -> 6 blocks/CU).
// ============================================================
__global__ __launch_bounds__(256) void k_act1(
    const int* __restrict__ item_id, const int* __restrict__ hist_ids,
    const int* __restrict__ attrs,
    const float* __restrict__ emb, const float* __restrict__ aub1,
    const float* __restrict__ auW2, const float* __restrict__ aub2,
    const short* __restrict__ bg_in, const float* __restrict__ wq_in,
    float* __restrict__ qp_out, float* __restrict__ ui1_out,
    float* __restrict__ cluster_out)
{
  __shared__ __align__(16) char sPool[16384];   // sB2 (16KB) then sAcc (16KB)
  __shared__ float sW1[208];
  __shared__ float sP[200];
  __shared__ float sM[KA], sE[KA];
  __shared__ float sItem[64], sQp[64];
  __shared__ float sQpP[4][64];
  __shared__ float sUi[4][64];
  __shared__ int   sIds[200], sAttr[200];

  short* sB2 = (short*)sPool;
  float (*sAcc)[KA][64] = (float (*)[KA][64])sPool;

  const int b = blockIdx.x;
  const int tid = threadIdx.x;
  const int wave = tid >> 6, lane = tid & 63;
  const int g = lane >> 4;
  const int c15 = lane & 15;
  const int itrow = item_id[b];

  for (int i = tid; i < 4096; i += 256)
    ((unsigned*)sB2)[i] = ((const unsigned*)bg_in)[i];
  if (tid < 64) sItem[tid] = emb[(size_t)itrow*64 + tid];
  if (tid < T_) {
    sIds[tid]  = hist_ids[(size_t)b*T_ + tid];
    sAttr[tid] = attrs[(size_t)b*T_ + tid];
  }
  __syncthreads();

  {
    const int j = tid & 63, iq = tid >> 6;
    float acc = 0.f;
    #pragma unroll
    for (int ii = 0; ii < 16; ++ii) {
      const int i = iq*16 + ii;
      acc += sItem[i] * wq_in[i*64 + j];
    }
    sQpP[iq][j] = acc;
  }
  __syncthreads();
  if (tid < 64) {
    float q = aub1[tid] + sQpP[0][tid] + sQpP[1][tid] + sQpP[2][tid] + sQpP[3][tid];
    sQp[tid] = q;
    qp_out[(size_t)b*64 + tid] = q;
  }
  __syncthreads();

  const float4* itemp = (const float4*)(emb + (size_t)itrow*64);
  float4 q0 = itemp[g*2],     q1 = itemp[g*2 + 1];
  float4 q2 = itemp[8 + g*2], q3 = itemp[8 + g*2 + 1];

  bf16x8 bfr[4][4];
  #pragma unroll
  for (int kk = 0; kk < 4; ++kk) {
    #pragma unroll
    for (int n = 0; n < 4; ++n)
      bfr[kk][n] = *(const bf16x8*)&sB2[(kk*4 + g)*512 + (n*16 + c15)*8];
  }
  float w2v[4], qpv[4];
  #pragma unroll
  for (int n = 0; n < 4; ++n) {
    w2v[n] = auW2[n*16 + c15];
    qpv[n] = sQp[n*16 + c15];
  }
  const float b2v = aub2[0];
  __syncthreads();                 // all waves done reading sB2

  for (int i = tid; i < 4*KA*64; i += 256) ((float*)sAcc)[i] = 0.f;

  // --- t-tiles: MFMA act-unit -> w1 scores into LDS (no prefetch) ---
  for (int tt = wave; tt < 13; tt += 4) {
    const int t = tt*16 + c15;
    float4 c0{0,0,0,0}, c1{0,0,0,0}, c2{0,0,0,0}, c3{0,0,0,0};
    if (t < T_) {
      const float4* kp = (const float4*)(emb + (size_t)sIds[t]*64);
      c0 = kp[g*2];     c1 = kp[g*2 + 1];
      c2 = kp[8 + g*2]; c3 = kp[8 + g*2 + 1];
    }

    bf16x8 a0 = pack8(c0, c1);
    bf16x8 a1 = pack8(c2, c3);
    bf16x8 a2 = pack8m(c0, c1, q0, q1);
    bf16x8 a3 = pack8m(c2, c3, q2, q3);

    f32x4 acc[4];
    #pragma unroll
    for (int n = 0; n < 4; ++n) acc[n] = f32x4{qpv[n], qpv[n], qpv[n], qpv[n]};
    #pragma unroll
    for (int n = 0; n < 4; ++n) {
      acc[n] = __builtin_amdgcn_mfma_f32_16x16x32_bf16(a0, bfr[0][n], acc[n], 0, 0, 0);
      acc[n] = __builtin_amdgcn_mfma_f32_16x16x32_bf16(a1, bfr[1][n], acc[n], 0, 0, 0);
      acc[n] = __builtin_amdgcn_mfma_f32_16x16x32_bf16(a2, bfr[2][n], acc[n], 0, 0, 0);
      acc[n] = __builtin_amdgcn_mfma_f32_16x16x32_bf16(a3, bfr[3][n], acc[n], 0, 0, 0);
    }
    float ws[4] = {0.f, 0.f, 0.f, 0.f};
    #pragma unroll
    for (int n = 0; n < 4; ++n) {
      #pragma unroll
      for (int r = 0; r < 4; ++r)
        ws[r] += fmaxf(acc[n][r], 0.f) * w2v[n];
    }
    #pragma unroll
    for (int r = 0; r < 4; ++r) {
      ws[r] += __shfl_xor(ws[r], 1);
      ws[r] += __shfl_xor(ws[r], 2);
      ws[r] += __shfl_xor(ws[r], 4);
      ws[r] += __shfl_xor(ws[r], 8);
      ws[r] += b2v;
    }
    if (c15 == 0) {
      #pragma unroll
      for (int r = 0; r < 4; ++r) {
        const int trow = tt*16 + g*4 + r;
        if (trow < T_) sW1[trow] = ws[r];
      }
    }
  }
  __syncthreads();

  for (int k = wave; k < KA; k += 4) {
    float m = -1e9f;
    for (int tt4 = 0; tt4 < 4; ++tt4) {
      int t = tt4*64 + lane;
      if (t < T_ && sAttr[t] == k) m = fmaxf(m, sW1[t]);
    }
    #pragma unroll
    for (int off = 32; off > 0; off >>= 1) m = fmaxf(m, __shfl_xor(m, off));
    float e = 0.f;
    for (int tt4 = 0; tt4 < 4; ++tt4) {
      int t = tt4*64 + lane;
      if (t < T_ && sAttr[t] == k) e += __expf(sW1[t] - m);
    }
    #pragma unroll
    for (int off = 32; off > 0; off >>= 1) e += __shfl_xor(e, off);
    if (lane == 0) { sM[k] = m; sE[k] = e; }
  }
  __syncthreads();
  if (tid < T_) {
    int k = sAttr[tid];
    float e = sE[k];
    sP[tid] = (e > 0.f) ? __expf(sW1[tid] - sM[k]) * __builtin_amdgcn_rcpf(e) : 0.f;
  }
  __syncthreads();

  {
    float uiacc = 0.f;
    float vcur = emb[(size_t)sIds[wave]*64 + lane];
    for (int t = wave; t < T_; t += 4) {
      const int tn = t + 4;
      float vnext = 0.f;
      if (tn < T_) vnext = emb[(size_t)sIds[tn]*64 + lane];
      const int k = sAttr[t];
      sAcc[wave][k][lane] += sP[t] * vcur;
      uiacc += sW1[t] * vcur;
      vcur = vnext;
    }
    sUi[wave][lane] = uiacc;
  }
  __syncthreads();

  for (int i = tid; i < KA*64; i += 256) {
    cluster_out[(size_t)b*(KA*64) + i] =
        sAcc[0][0][i] + sAcc[1][0][i] + sAcc[2][0][i] + sAcc[3][0][i];
  }
  if (tid < 64) {
    ui1_out[(size_t)b*64 + tid] =
        sUi[0][tid] + sUi[1][tid] + sUi[2][tid] + sUi[3][tid];
  }
}

// ============================================================
// K3 (MFMA): GRU, 16 rows/block, producer-consumer.
// ============================================================
#define GRU_ROWS 16
__global__ __launch_bounds__(512) void k_gru(
    const int* __restrict__ hist_ids, const float* __restrict__ emb,
    const float* __restrict__ Wx, const float* __restrict__ Wh,
    const float* __restrict__ gb, float* __restrict__ hfin_out)
{
  __shared__ short sH[2][16*64];
  __shared__ short sX[4][16*64];
  __shared__ int   sIds[16*200];

  const int tid  = threadIdx.x;
  const int w    = tid >> 6;
  const int lane = tid & 63;
  const int g    = lane >> 4;
  const int c15  = lane & 15;
  const int b0   = blockIdx.x * GRU_ROWS;

  for (int i = tid; i < 16*200; i += 512) {
    const int r = i / 200, t = i - r*200;
    sIds[i] = hist_ids[(size_t)(b0 + r)*T_ + t];
  }
  for (int i = tid; i < 16*64; i += 512) sH[0][i] = 0;
  __syncthreads();

  if (w >= 4) {
    const int stane = (w - 4)*64 + lane;
    const int srow  = stane >> 4;
    const int scol  = (stane & 15) * 4;
    const int sidx  = srow*64 + (((scol >> 3) ^ (srow & 7))*8) + (scol & 7);
    const int* idrow = &sIds[srow*200];
    #pragma unroll
    for (int p = 0; p < 2; ++p) {
      const float4 f = *(const float4*)(emb + (size_t)idrow[p]*64 + scol);
      uint2 u; u.x = cvtpk(f.x, f.y); u.y = cvtpk(f.z, f.w);
      *(uint2*)&sX[p][sidx] = u;
    }
    __syncthreads();
    for (int t = 0; t < T_; ++t) {
      const int t2 = (t + 2 < T_) ? (t + 2) : (T_ - 1);
      const float4 f = *(const float4*)(emb + (size_t)idrow[t2]*64 + scol);
      uint2 u; u.x = cvtpk(f.x, f.y); u.y = cvtpk(f.z, f.w);
      *(uint2*)&sX[(t + 2) & 3][sidx] = u;
      __syncthreads();
    }
  } else {
    bf16x8 bx[3][2], bh[3][2];
    #pragma unroll
    for (int l = 0; l < 3; ++l) {
      const int jb = (l*4 + w)*16 + c15;
      #pragma unroll
      for (int kk = 0; kk < 2; ++kk) {
        bf16x8 vx, vh;
        #pragma unroll
        for (int e = 0; e < 8; ++e) {
          const int krow = kk*32 + g*8 + e;
          vx[e] = f2bf(Wx[(size_t)krow*192 + jb]);
          vh[e] = f2bf(Wh[(size_t)krow*192 + jb]);
        }
        bx[l][kk] = vx; bh[l][kk] = vh;
      }
    }
    float bias[3];
    #pragma unroll
    for (int l = 0; l < 3; ++l) bias[l] = gb[l*64 + w*16 + c15];

    const int rs = c15 & 7;
    const int ridx0 = c15*64 + ((g    ) ^ rs)*8;
    const int ridx1 = c15*64 + ((g + 4) ^ rs)*8;
    int widx[4];
    {
      const int unit = w*2 + (c15 >> 3);
      #pragma unroll
      for (int r = 0; r < 4; ++r) {
        const int row = g*4 + r;
        widx[r] = row*64 + ((unit ^ (row & 7))*8) + (c15 & 7);
      }
    }
    float hold[4] = {0.f, 0.f, 0.f, 0.f};
    __syncthreads();

    #pragma unroll 2
    for (int t = 0; t < T_; ++t) {
      const short* hbuf = sH[t & 1];
      short*       hnxt = sH[(t & 1) ^ 1];
      const short* xbuf = sX[t & 3];

      bf16x8 ax0 = *(const bf16x8*)&xbuf[ridx0];
      bf16x8 ax1 = *(const bf16x8*)&xbuf[ridx1];
      bf16x8 ah0 = *(const bf16x8*)&hbuf[ridx0];
      bf16x8 ah1 = *(const bf16x8*)&hbuf[ridx1];

      f32x4 aX[3], aH[3];
      #pragma unroll
      for (int l = 0; l < 3; ++l) {
        aX[l] = f32x4{bias[l], bias[l], bias[l], bias[l]};
        aH[l] = f32x4{0.f, 0.f, 0.f, 0.f};
      }
      #pragma unroll
      for (int l = 0; l < 3; ++l) {
        aH[l] = __builtin_amdgcn_mfma_f32_16x16x32_bf16(ah0, bh[l][0], aH[l], 0, 0, 0);
        aH[l] = __builtin_amdgcn_mfma_f32_16x16x32_bf16(ah1, bh[l][1], aH[l], 0, 0, 0);
        aX[l] = __builtin_amdgcn_mfma_f32_16x16x32_bf16(ax0, bx[l][0], aX[l], 0, 0, 0);
        aX[l] = __builtin_amdgcn_mfma_f32_16x16x32_bf16(ax1, bx[l][1], aX[l], 0, 0, 0);
      }

      #pragma unroll
      for (int r = 0; r < 4; ++r) {
        float z  = sigf(aX[0][r] + aH[0][r]);
        float rr = sigf(aX[1][r] + aH[1][r]);
        float nn = tanhfast(aX[2][r] + rr * aH[2][r]);
        hold[r] = nn + z * (hold[r] - nn);
        hnxt[widx[r]] = f2bf(hold[r]);
      }
      __syncthreads();
    }

    #pragma unroll
    for (int r = 0; r < 4; ++r)
      hfin_out[(size_t)(b0 + g*4 + r)*64 + w*16 + c15] = hold[r];
  }
}

// ============================================================
// K4 (MFMA): activation unit over 16 clusters -> ui_l2[b,64]
// ============================================================
__global__ __launch_bounds__(256) void k_act2(
    const int* __restrict__ item_id, const float* __restrict__ emb,
    const float* __restrict__ auW2, const float* __restrict__ aub2,
    const float* __restrict__ qp_in, const float* __restrict__ cluster_in,
    const short* __restrict__ bg_in, float* __restrict__ ui2_out)
{
  __shared__ short sB2[8192];
  __shared__ float sWs[4][16];
  __shared__ float sWf[16];
  __shared__ float sUi[4][64];

  const int b = blockIdx.x;
  const int tid = threadIdx.x;
  const int wave = tid >> 6, lane = tid & 63;
  const int g = lane >> 4;
  const int c15 = lane & 15;
  const int itrow = item_id[b];

  for (int i = tid; i < 4096; i += 256)
    ((unsigned*)sB2)[i] = ((const unsigned*)bg_in)[i];
  __syncthreads();

  const float4* itemp = (const float4*)(emb + (size_t)itrow*64);
  float4 q0 = itemp[g*2],     q1 = itemp[g*2 + 1];
  float4 q2 = itemp[8 + g*2], q3 = itemp[8 + g*2 + 1];
  const float4* kp = (const float4*)(cluster_in + (size_t)b*(KA*64) + c15*64);
  float4 k0 = kp[g*2],     k1 = kp[g*2 + 1];
  float4 k2 = kp[8 + g*2], k3 = kp[8 + g*2 + 1];
  bf16x8 a0 = pack8(k0, k1);
  bf16x8 a1 = pack8(k2, k3);
  bf16x8 a2 = pack8m(k0, k1, q0, q1);
  bf16x8 a3 = pack8m(k2, k3, q2, q3);

  const float qpv = qp_in[(size_t)b*64 + wave*16 + c15];
  const float w2v = auW2[wave*16 + c15];
  f32x4 acc = f32x4{qpv, qpv, qpv, qpv};
  acc = __builtin_amdgcn_mfma_f32_16x16x32_bf16(a0, *(const bf16x8*)&sB2[(0*4+g)*512 + (wave*16+c15)*8], acc, 0, 0, 0);
  acc = __builtin_amdgcn_mfma_f32_16x16x32_bf16(a1, *(const bf16x8*)&sB2[(1*4+g)*512 + (wave*16+c15)*8], acc, 0, 0, 0);
  acc = __builtin_amdgcn_mfma_f32_16x16x32_bf16(a2, *(const bf16x8*)&sB2[(2*4+g)*512 + (wave*16+c15)*8], acc, 0, 0, 0);
  acc = __builtin_amdgcn_mfma_f32_16x16x32_bf16(a3, *(const bf16x8*)&sB2[(3*4+g)*512 + (wave*16+c15)*8], acc, 0, 0, 0);

  float ws[4];
  #pragma unroll
  for (int r = 0; r < 4; ++r) {
    float v = fmaxf(acc[r], 0.f) * w2v;
    v += __shfl_xor(v, 1);
    v += __shfl_xor(v, 2);
    v += __shfl_xor(v, 4);
    v += __shfl_xor(v, 8);
    ws[r] = v;
  }
  if (c15 == 0) {
    #pragma unroll
    for (int r = 0; r < 4; ++r) sWs[wave][g*4 + r] = ws[r];
  }
  __syncthreads();
  if (tid < KA)
    sWf[tid] = sWs[0][tid] + sWs[1][tid] + sWs[2][tid] + sWs[3][tid] + aub2[0];
  __syncthreads();

  float uiacc = 0.f;
  #pragma unroll
  for (int kk = 0; kk < 4; ++kk) {
    const int k = wave*4 + kk;
    uiacc += sWf[k] * cluster_in[(size_t)b*(KA*64) + k*64 + lane];
  }
  sUi[wave][lane] = uiacc;
  __syncthreads();
  if (tid < 64) {
    ui2_out[(size_t)b*64 + tid] =
        sUi[0][tid] + sUi[1][tid] + sUi[2][tid] + sUi[3][tid];
  }
}

// ============================================================
// K5: final MLP
// ============================================================
#define MLP_ROWS 16
__global__ __launch_bounds__(256) void k_mlp(
    const int* __restrict__ item_id, const float* __restrict__ emb,
    const float* __restrict__ ui1, const float* __restrict__ ui2,
    const float* __restrict__ hfin,
    const float* __restrict__ W0, const float* __restrict__ b0,
    const float* __restrict__ W1, const float* __restrict__ b1,
    const float* __restrict__ fW, const float* __restrict__ fb,
    float* __restrict__ out)
{
  __shared__ float sC[MLP_ROWS][256];
  __shared__ float sX0[MLP_ROWS][256];
  __shared__ float sX1[MLP_ROWS][128];
  const int tid = threadIdx.x;
  const int rb  = blockIdx.x * MLP_ROWS;

  for (int idx = tid; idx < MLP_ROWS*256; idx += 256) {
    int r = idx >> 8, c = idx & 255;
    size_t row = (size_t)(rb + r);
    float v;
    if (c < 64)       v = ui1[row*64 + c];
    else if (c < 128) v = ui2[row*64 + (c-64)];
    else if (c < 192) v = hfin[row*64 + (c-128)];
    else              v = emb[(size_t)item_id[row]*64 + (c-192)];
    sC[r][c] = v;
  }
  __syncthreads();
  {
    float acc[MLP_ROWS];
    #pragma unroll
    for (int r = 0; r < MLP_ROWS; ++r) acc[r] = b0[tid];
    #pragma unroll 4
    for (int i = 0; i < 256; ++i) {
      float w = W0[(size_t)i*256 + tid];
      #pragma unroll
      for (int r = 0; r < MLP_ROWS; ++r) acc[r] += sC[r][i] * w;
    }
    #pragma unroll
    for (int r = 0; r < MLP_ROWS; ++r) sX0[r][tid] = fmaxf(acc[r], 0.f);
  }
  __syncthreads();
  if (tid < 128) {
    float acc[MLP_ROWS];
    #pragma unroll
    for (int r = 0; r < MLP_ROWS; ++r) acc[r] = b1[tid];
    #pragma unroll 4
    for (int i = 0; i < 256; ++i) {
      float w = W1[(size_t)i*128 + tid];
      #pragma unroll
      for (int r = 0; r < MLP_ROWS; ++r) acc[r] += sX0[r][i] * w;
    }
    #pragma unroll
    for (int r = 0; r < MLP_ROWS; ++r) sX1[r][tid] = fmaxf(acc[r], 0.f);
  }
  __syncthreads();
  {
    int r = tid >> 4, l16 = tid & 15;
    float p = 0.f;
    for (int i = l16; i < 128; i += 16) p += sX1[r][i] * fW[i];
    #pragma unroll
    for (int off = 8; off > 0; off >>= 1) p += __shfl_xor(p, off);
    if (l16 == 0) {
      float logit = p + fb[0];
      out[rb + r] = sigmoidf_(logit);
    }
  }
}

// ============================================================
extern "C" void kernel_launch(void* const* d_in, const int* in_sizes, int n_in,
                              void* d_out, int out_size, void* d_ws, size_t ws_size,
                              hipStream_t stream)
{
  const int*   item_id  = (const int*)d_in[0];
  const int*   hist_ids = (const int*)d_in[1];
  const int*   attrs    = (const int*)d_in[2];
  const float* emb      = (const float*)d_in[3];
  const float* auW1     = (const float*)d_in[4];
  const float* aub1     = (const float*)d_in[5];
  const float* auW2     = (const float*)d_in[6];
  const float* aub2     = (const float*)d_in[7];
  const float* gWx      = (const float*)d_in[8];
  const float* gWh      = (const float*)d_in[9];
  const float* gb       = (const float*)d_in[10];
  const float* W0       = (const float*)d_in[11];
  const float* b0       = (const float*)d_in[12];
  const float* W1       = (const float*)d_in[13];
  const float* b1       = (const float*)d_in[14];
  const float* fW       = (const float*)d_in[15];
  const float* fb       = (const float*)d_in[16];

  float* out = (float*)d_out;
  float* ws  = (float*)d_ws;
  short* bg      = (short*)(ws + OFF_BG);
  float* wq      = ws + OFF_WQ;
  float* qp      = ws + OFF_QP;
  float* ui1     = ws + OFF_UI1;
  float* ui2     = ws + OFF_UI2;
  float* hfin    = ws + OFF_HF;
  float* cluster = ws + OFF_CL;

  k_prep<<<48, 256, 0, stream>>>(auW1, bg, wq);
  k_act1<<<B_, 256, 0, stream>>>(item_id, hist_ids, attrs, emb, aub1,
                                 auW2, aub2, bg, wq, qp, ui1, cluster);
  k_gru<<<B_/GRU_ROWS, 512, 0, stream>>>(hist_ids, emb, gWx, gWh, gb, hfin);
  k_act2<<<B_, 256, 0, stream>>>(item_id, emb, auW2, aub2, qp, cluster, bg,
                                 ui2);
  k_mlp<<<B_/MLP_ROWS, 256, 0, stream>>>(item_id, emb, ui1, ui2, hfin,
                                         W0, b0, W1, b1, fW, fb, out);
}